// Round 1
// baseline (724.734 us; speedup 1.0000x reference)
//
#include <hip/hip_runtime.h>
#include <math.h>

static constexpr int BB = 16;
static constexpr int NN = 100000;
static constexpr int GN = 4096;
static constexpr int GS = 64;
static constexpr int NP = BB * GN;  // 65536 problems

__device__ __forceinline__ float wsum64(float v) {
#pragma unroll
  for (int off = 32; off > 0; off >>= 1) v += __shfl_xor(v, off, 64);
  return v;
}

// ---------------- Kernel A: per-(b,g) stats: muX, muY, H ----------------
__global__ __launch_bounds__(256) void k_stats(
    const float* __restrict__ x, const float* __restrict__ tpl,
    const int* __restrict__ groups, float* __restrict__ Ht) {
  int wid  = blockIdx.x * 4 + (threadIdx.x >> 6);  // problem id
  int lane = threadIdx.x & 63;
  int b = wid >> 12;          // / GN
  int g = wid & (GN - 1);
  int idx = groups[g * GS + lane];
  float y0 = tpl[idx * 3 + 0], y1 = tpl[idx * 3 + 1], y2 = tpl[idx * 3 + 2];
  const float* xp = x + ((size_t)b * NN + (size_t)idx) * 3;
  float x0 = xp[0], x1 = xp[1], x2 = xp[2];

  float sx0 = wsum64(x0), sx1 = wsum64(x1), sx2 = wsum64(x2);
  float sy0 = wsum64(y0), sy1 = wsum64(y1), sy2 = wsum64(y2);
  float h00 = wsum64(y0 * x0), h01 = wsum64(y0 * x1), h02 = wsum64(y0 * x2);
  float h10 = wsum64(y1 * x0), h11 = wsum64(y1 * x1), h12 = wsum64(y1 * x2);
  float h20 = wsum64(y2 * x0), h21 = wsum64(y2 * x1), h22 = wsum64(y2 * x2);

  if (lane == 0) {
    const float inv = 1.0f / 64.0f;
    float mx0 = sx0 * inv, mx1 = sx1 * inv, mx2 = sx2 * inv;
    float my0 = sy0 * inv, my1 = sy1 * inv, my2 = sy2 * inv;
    float* o = Ht + (size_t)wid * 16;
    o[0] = mx0; o[1] = mx1; o[2] = mx2;
    o[3] = my0; o[4] = my1; o[5] = my2;
    // H[i][j] = sum(y_i x_j) - sy_i * mx_j
    o[6]  = h00 - sy0 * mx0; o[7]  = h01 - sy0 * mx1; o[8]  = h02 - sy0 * mx2;
    o[9]  = h10 - sy1 * mx0; o[10] = h11 - sy1 * mx1; o[11] = h12 - sy1 * mx2;
    o[12] = h20 - sy2 * mx0; o[13] = h21 - sy2 * mx1; o[14] = h22 - sy2 * mx2;
    o[15] = 0.0f;
  }
}

// ---------------- Kernel B: per-thread 3x3 SVD -> R, t ----------------
// Jacobi rotation on symmetric K, columns of V accumulated. Literal indices only.
#define JROT(P, Q, RR)                                                        \
  {                                                                           \
    float apq = K[P][Q];                                                      \
    if (fabsf(apq) > 1e-30f) {                                                \
      float app = K[P][P], aqq = K[Q][Q];                                     \
      float tau = (aqq - app) / (2.0f * apq);                                 \
      float tt = copysignf(1.0f, tau) / (fabsf(tau) + sqrtf(1.0f + tau*tau)); \
      float cc = 1.0f / sqrtf(1.0f + tt * tt);                                \
      float ss = tt * cc;                                                     \
      K[P][P] = app - tt * apq;                                               \
      K[Q][Q] = aqq + tt * apq;                                               \
      K[P][Q] = 0.0f; K[Q][P] = 0.0f;                                         \
      float krp = K[RR][P], krq = K[RR][Q];                                   \
      K[RR][P] = cc * krp - ss * krq; K[P][RR] = K[RR][P];                    \
      K[RR][Q] = ss * krp + cc * krq; K[Q][RR] = K[RR][Q];                    \
      float v0p = V[0][P], v0q = V[0][Q];                                     \
      float v1p = V[1][P], v1q = V[1][Q];                                     \
      float v2p = V[2][P], v2q = V[2][Q];                                     \
      V[0][P] = cc * v0p - ss * v0q; V[0][Q] = ss * v0p + cc * v0q;           \
      V[1][P] = cc * v1p - ss * v1q; V[1][Q] = ss * v1p + cc * v1q;           \
      V[2][P] = cc * v2p - ss * v2q; V[2][Q] = ss * v2p + cc * v2q;           \
    }                                                                         \
  }

// Finish: R = va*ua^T + vb*ub^T + dsg * vc * (ua x ub)^T, (AA,BBi,CC) cyclic,
// CC = argmin eigenvalue.
#define FIN(AA, BBi, CC)                                                      \
  {                                                                           \
    float va0 = V[0][AA], va1 = V[1][AA], va2 = V[2][AA];                     \
    float vb0 = V[0][BBi], vb1 = V[1][BBi], vb2 = V[2][BBi];                  \
    float vc0 = V[0][CC], vc1 = V[1][CC], vc2 = V[2][CC];                     \
    float ua0 = A[0][0]*va0 + A[0][1]*va1 + A[0][2]*va2;                      \
    float ua1 = A[1][0]*va0 + A[1][1]*va1 + A[1][2]*va2;                      \
    float ua2 = A[2][0]*va0 + A[2][1]*va1 + A[2][2]*va2;                      \
    float il = 1.0f / sqrtf(ua0*ua0 + ua1*ua1 + ua2*ua2 + 1e-30f);            \
    ua0 *= il; ua1 *= il; ua2 *= il;                                          \
    float ub0 = A[0][0]*vb0 + A[0][1]*vb1 + A[0][2]*vb2;                      \
    float ub1 = A[1][0]*vb0 + A[1][1]*vb1 + A[1][2]*vb2;                      \
    float ub2 = A[2][0]*vb0 + A[2][1]*vb1 + A[2][2]*vb2;                      \
    il = 1.0f / sqrtf(ub0*ub0 + ub1*ub1 + ub2*ub2 + 1e-30f);                  \
    ub0 *= il; ub1 *= il; ub2 *= il;                                          \
    float dd = ua0*ub0 + ua1*ub1 + ua2*ub2;                                   \
    ub0 -= dd * ua0; ub1 -= dd * ua1; ub2 -= dd * ua2;                        \
    il = 1.0f / sqrtf(ub0*ub0 + ub1*ub1 + ub2*ub2 + 1e-30f);                  \
    ub0 *= il; ub1 *= il; ub2 *= il;                                          \
    float uc0 = ua1*ub2 - ua2*ub1;                                            \
    float uc1 = ua2*ub0 - ua0*ub2;                                            \
    float uc2 = ua0*ub1 - ua1*ub0;                                            \
    R[0][0] = va0*ua0 + vb0*ub0 + dsg*vc0*uc0;                                \
    R[0][1] = va0*ua1 + vb0*ub1 + dsg*vc0*uc1;                                \
    R[0][2] = va0*ua2 + vb0*ub2 + dsg*vc0*uc2;                                \
    R[1][0] = va1*ua0 + vb1*ub0 + dsg*vc1*uc0;                                \
    R[1][1] = va1*ua1 + vb1*ub1 + dsg*vc1*uc1;                                \
    R[1][2] = va1*ua2 + vb1*ub2 + dsg*vc1*uc2;                                \
    R[2][0] = va2*ua0 + vb2*ub0 + dsg*vc2*uc0;                                \
    R[2][1] = va2*ua1 + vb2*ub1 + dsg*vc2*uc1;                                \
    R[2][2] = va2*ua2 + vb2*ub2 + dsg*vc2*uc2;                                \
  }

__global__ __launch_bounds__(256) void k_svd(
    const float* __restrict__ Ht, float* __restrict__ Rt) {
  int p = blockIdx.x * 256 + threadIdx.x;
  if (p >= NP) return;
  const float* h = Ht + (size_t)p * 16;
  float mx0 = h[0], mx1 = h[1], mx2 = h[2];
  float my0 = h[3], my1 = h[4], my2 = h[5];
  float A[3][3];
  A[0][0] = h[6];  A[0][1] = h[7];  A[0][2] = h[8];
  A[1][0] = h[9];  A[1][1] = h[10]; A[1][2] = h[11];
  A[2][0] = h[12]; A[2][1] = h[13]; A[2][2] = h[14];

  float K[3][3];
#pragma unroll
  for (int i = 0; i < 3; ++i)
#pragma unroll
    for (int j = 0; j < 3; ++j)
      K[i][j] = A[0][i]*A[0][j] + A[1][i]*A[1][j] + A[2][i]*A[2][j];

  float V[3][3] = {{1.f,0.f,0.f},{0.f,1.f,0.f},{0.f,0.f,1.f}};
#pragma unroll
  for (int sweep = 0; sweep < 5; ++sweep) {
    JROT(0, 1, 2);
    JROT(0, 2, 1);
    JROT(1, 2, 0);
  }

  float d0 = K[0][0], d1 = K[1][1], d2 = K[2][2];
  float detV = V[0][0]*(V[1][1]*V[2][2] - V[1][2]*V[2][1])
             - V[0][1]*(V[1][0]*V[2][2] - V[1][2]*V[2][0])
             + V[0][2]*(V[1][0]*V[2][1] - V[1][1]*V[2][0]);
  float dsg = (detV < 0.0f) ? -1.0f : 1.0f;

  float R[3][3];
  if (d0 <= d1 && d0 <= d2) {
    FIN(1, 2, 0);
  } else if (d1 <= d0 && d1 <= d2) {
    FIN(2, 0, 1);
  } else {
    FIN(0, 1, 2);
  }

  float t0 = mx0 - (R[0][0]*my0 + R[0][1]*my1 + R[0][2]*my2);
  float t1 = mx1 - (R[1][0]*my0 + R[1][1]*my1 + R[1][2]*my2);
  float t2 = mx2 - (R[2][0]*my0 + R[2][1]*my1 + R[2][2]*my2);

  float* o = Rt + (size_t)p * 12;
  o[0] = R[0][0]; o[1] = R[0][1]; o[2] = R[0][2];
  o[3] = R[1][0]; o[4] = R[1][1]; o[5] = R[1][2];
  o[6] = R[2][0]; o[7] = R[2][1]; o[8] = R[2][2];
  o[9] = t0; o[10] = t1; o[11] = t2;
}

// ---------------- Kernel: counts histogram ----------------
__global__ __launch_bounds__(256) void k_counts(
    const int* __restrict__ groups, float* __restrict__ counts) {
  int t = blockIdx.x * 256 + threadIdx.x;
  if (t < GN * GS) atomicAdd(&counts[groups[t]], 1.0f);
}

// ---------------- Kernel C: project + scatter-add ----------------
__global__ __launch_bounds__(256) void k_scatter(
    const float* __restrict__ tpl, const int* __restrict__ groups,
    const float* __restrict__ Rt, float* __restrict__ out) {
  int wid  = blockIdx.x * 4 + (threadIdx.x >> 6);
  int lane = threadIdx.x & 63;
  int b = wid >> 12;
  int g = wid & (GN - 1);
  int idx = groups[g * GS + lane];
  float y0 = tpl[idx * 3 + 0], y1 = tpl[idx * 3 + 1], y2 = tpl[idx * 3 + 2];
  const float* rt = Rt + (size_t)wid * 12;
  float r00 = rt[0], r01 = rt[1], r02 = rt[2];
  float r10 = rt[3], r11 = rt[4], r12 = rt[5];
  float r20 = rt[6], r21 = rt[7], r22 = rt[8];
  float t0 = rt[9], t1 = rt[10], t2 = rt[11];
  float p0 = r00*y0 + r01*y1 + r02*y2 + t0;
  float p1 = r10*y0 + r11*y1 + r12*y2 + t1;
  float p2 = r20*y0 + r21*y1 + r22*y2 + t2;
  float* o = out + ((size_t)b * NN + (size_t)idx) * 3;
  atomicAdd(o + 0, p0);
  atomicAdd(o + 1, p1);
  atomicAdd(o + 2, p2);
}

// ---------------- Kernel D: divide by counts ----------------
__global__ __launch_bounds__(256) void k_div(
    float* __restrict__ out, const float* __restrict__ counts) {
  int t = blockIdx.x * 256 + threadIdx.x;
  if (t >= BB * NN) return;
  int n = t % NN;
  float inv = 1.0f / fmaxf(counts[n], 1.0f);
  float* o = out + (size_t)t * 3;
  o[0] *= inv; o[1] *= inv; o[2] *= inv;
}

extern "C" void kernel_launch(void* const* d_in, const int* in_sizes, int n_in,
                              void* d_out, int out_size, void* d_ws, size_t ws_size,
                              hipStream_t stream) {
  const float* x      = (const float*)d_in[0];  // (B,N,3) f32
  const float* tpl    = (const float*)d_in[1];  // (N,3) f32
  const int*   groups = (const int*)d_in[2];    // (GN,GS) i32
  float* out = (float*)d_out;

  char* ws = (char*)d_ws;
  float* Ht = (float*)ws;                                     // NP*16 f32 = 4 MB
  float* Rt = (float*)(ws + (size_t)NP * 16 * 4);             // NP*12 f32 = 3 MB
  float* counts = (float*)(ws + (size_t)NP * 16 * 4 + (size_t)NP * 12 * 4);  // N f32

  hipMemsetAsync(d_out, 0, (size_t)out_size * sizeof(float), stream);
  hipMemsetAsync(counts, 0, (size_t)NN * sizeof(float), stream);

  k_stats<<<NP / 4, 256, 0, stream>>>(x, tpl, groups, Ht);
  k_svd<<<NP / 256, 256, 0, stream>>>(Ht, Rt);
  k_counts<<<(GN * GS) / 256, 256, 0, stream>>>(groups, counts);
  k_scatter<<<NP / 4, 256, 0, stream>>>(tpl, groups, Rt, out);
  k_div<<<(BB * NN + 255) / 256, 256, 0, stream>>>(out, counts);
}

// Round 2
// 149.913 us; speedup vs baseline: 4.8344x; 4.8344x over previous
//
#include <hip/hip_runtime.h>
#include <math.h>

static constexpr int BB = 16;
static constexpr int NN = 100000;
static constexpr int GN = 4096;
static constexpr int GS = 64;
static constexpr int NP = BB * GN;       // 65536 problems
static constexpr int NE = GN * GS;       // 262144 entries
static constexpr int NBLK = (NN + 255) / 256;  // 391

__device__ __forceinline__ float wsum64(float v) {
#pragma unroll
  for (int off = 32; off > 0; off >>= 1) v += __shfl_xor(v, off, 64);
  return v;
}

// ---------------- Kernel A: per-(b,g) stats: muX, muY, H ----------------
__global__ __launch_bounds__(256) void k_stats(
    const float* __restrict__ x, const float* __restrict__ tpl,
    const int* __restrict__ groups, float* __restrict__ Ht) {
  int wid  = blockIdx.x * 4 + (threadIdx.x >> 6);  // problem id
  int lane = threadIdx.x & 63;
  int b = wid >> 12;          // / GN
  int g = wid & (GN - 1);
  int idx = groups[g * GS + lane];
  float y0 = tpl[idx * 3 + 0], y1 = tpl[idx * 3 + 1], y2 = tpl[idx * 3 + 2];
  const float* xp = x + ((size_t)b * NN + (size_t)idx) * 3;
  float x0 = xp[0], x1 = xp[1], x2 = xp[2];

  float sx0 = wsum64(x0), sx1 = wsum64(x1), sx2 = wsum64(x2);
  float sy0 = wsum64(y0), sy1 = wsum64(y1), sy2 = wsum64(y2);
  float h00 = wsum64(y0 * x0), h01 = wsum64(y0 * x1), h02 = wsum64(y0 * x2);
  float h10 = wsum64(y1 * x0), h11 = wsum64(y1 * x1), h12 = wsum64(y1 * x2);
  float h20 = wsum64(y2 * x0), h21 = wsum64(y2 * x1), h22 = wsum64(y2 * x2);

  if (lane == 0) {
    const float inv = 1.0f / 64.0f;
    float mx0 = sx0 * inv, mx1 = sx1 * inv, mx2 = sx2 * inv;
    float my0 = sy0 * inv, my1 = sy1 * inv, my2 = sy2 * inv;
    float* o = Ht + (size_t)wid * 16;
    o[0] = mx0; o[1] = mx1; o[2] = mx2;
    o[3] = my0; o[4] = my1; o[5] = my2;
    // H[i][j] = sum(y_i x_j) - sy_i * mx_j
    o[6]  = h00 - sy0 * mx0; o[7]  = h01 - sy0 * mx1; o[8]  = h02 - sy0 * mx2;
    o[9]  = h10 - sy1 * mx0; o[10] = h11 - sy1 * mx1; o[11] = h12 - sy1 * mx2;
    o[12] = h20 - sy2 * mx0; o[13] = h21 - sy2 * mx1; o[14] = h22 - sy2 * mx2;
    o[15] = 0.0f;
  }
}

// ---------------- Kernel B: per-thread 3x3 SVD -> R, t ----------------
#define JROT(P, Q, RR)                                                        \
  {                                                                           \
    float apq = K[P][Q];                                                      \
    if (fabsf(apq) > 1e-30f) {                                                \
      float app = K[P][P], aqq = K[Q][Q];                                     \
      float tau = (aqq - app) / (2.0f * apq);                                 \
      float tt = copysignf(1.0f, tau) / (fabsf(tau) + sqrtf(1.0f + tau*tau)); \
      float cc = 1.0f / sqrtf(1.0f + tt * tt);                                \
      float ss = tt * cc;                                                     \
      K[P][P] = app - tt * apq;                                               \
      K[Q][Q] = aqq + tt * apq;                                               \
      K[P][Q] = 0.0f; K[Q][P] = 0.0f;                                         \
      float krp = K[RR][P], krq = K[RR][Q];                                   \
      K[RR][P] = cc * krp - ss * krq; K[P][RR] = K[RR][P];                    \
      K[RR][Q] = ss * krp + cc * krq; K[Q][RR] = K[RR][Q];                    \
      float v0p = V[0][P], v0q = V[0][Q];                                     \
      float v1p = V[1][P], v1q = V[1][Q];                                     \
      float v2p = V[2][P], v2q = V[2][Q];                                     \
      V[0][P] = cc * v0p - ss * v0q; V[0][Q] = ss * v0p + cc * v0q;           \
      V[1][P] = cc * v1p - ss * v1q; V[1][Q] = ss * v1p + cc * v1q;           \
      V[2][P] = cc * v2p - ss * v2q; V[2][Q] = ss * v2p + cc * v2q;           \
    }                                                                         \
  }

#define FIN(AA, BBi, CC)                                                      \
  {                                                                           \
    float va0 = V[0][AA], va1 = V[1][AA], va2 = V[2][AA];                     \
    float vb0 = V[0][BBi], vb1 = V[1][BBi], vb2 = V[2][BBi];                  \
    float vc0 = V[0][CC], vc1 = V[1][CC], vc2 = V[2][CC];                     \
    float ua0 = A[0][0]*va0 + A[0][1]*va1 + A[0][2]*va2;                      \
    float ua1 = A[1][0]*va0 + A[1][1]*va1 + A[1][2]*va2;                      \
    float ua2 = A[2][0]*va0 + A[2][1]*va1 + A[2][2]*va2;                      \
    float il = 1.0f / sqrtf(ua0*ua0 + ua1*ua1 + ua2*ua2 + 1e-30f);            \
    ua0 *= il; ua1 *= il; ua2 *= il;                                          \
    float ub0 = A[0][0]*vb0 + A[0][1]*vb1 + A[0][2]*vb2;                      \
    float ub1 = A[1][0]*vb0 + A[1][1]*vb1 + A[1][2]*vb2;                      \
    float ub2 = A[2][0]*vb0 + A[2][1]*vb1 + A[2][2]*vb2;                      \
    il = 1.0f / sqrtf(ub0*ub0 + ub1*ub1 + ub2*ub2 + 1e-30f);                  \
    ub0 *= il; ub1 *= il; ub2 *= il;                                          \
    float dd = ua0*ub0 + ua1*ub1 + ua2*ub2;                                   \
    ub0 -= dd * ua0; ub1 -= dd * ua1; ub2 -= dd * ua2;                        \
    il = 1.0f / sqrtf(ub0*ub0 + ub1*ub1 + ub2*ub2 + 1e-30f);                  \
    ub0 *= il; ub1 *= il; ub2 *= il;                                          \
    float uc0 = ua1*ub2 - ua2*ub1;                                            \
    float uc1 = ua2*ub0 - ua0*ub2;                                            \
    float uc2 = ua0*ub1 - ua1*ub0;                                            \
    R[0][0] = va0*ua0 + vb0*ub0 + dsg*vc0*uc0;                                \
    R[0][1] = va0*ua1 + vb0*ub1 + dsg*vc0*uc1;                                \
    R[0][2] = va0*ua2 + vb0*ub2 + dsg*vc0*uc2;                                \
    R[1][0] = va1*ua0 + vb1*ub0 + dsg*vc1*uc0;                                \
    R[1][1] = va1*ua1 + vb1*ub1 + dsg*vc1*uc1;                                \
    R[1][2] = va1*ua2 + vb1*ub2 + dsg*vc1*uc2;                                \
    R[2][0] = va2*ua0 + vb2*ub0 + dsg*vc2*uc0;                                \
    R[2][1] = va2*ua1 + vb2*ub1 + dsg*vc2*uc1;                                \
    R[2][2] = va2*ua2 + vb2*ub2 + dsg*vc2*uc2;                                \
  }

__global__ __launch_bounds__(256) void k_svd(
    const float* __restrict__ Ht, float* __restrict__ Rt) {
  int p = blockIdx.x * 256 + threadIdx.x;
  if (p >= NP) return;
  const float* h = Ht + (size_t)p * 16;
  float mx0 = h[0], mx1 = h[1], mx2 = h[2];
  float my0 = h[3], my1 = h[4], my2 = h[5];
  float A[3][3];
  A[0][0] = h[6];  A[0][1] = h[7];  A[0][2] = h[8];
  A[1][0] = h[9];  A[1][1] = h[10]; A[1][2] = h[11];
  A[2][0] = h[12]; A[2][1] = h[13]; A[2][2] = h[14];

  float K[3][3];
#pragma unroll
  for (int i = 0; i < 3; ++i)
#pragma unroll
    for (int j = 0; j < 3; ++j)
      K[i][j] = A[0][i]*A[0][j] + A[1][i]*A[1][j] + A[2][i]*A[2][j];

  float V[3][3] = {{1.f,0.f,0.f},{0.f,1.f,0.f},{0.f,0.f,1.f}};
#pragma unroll
  for (int sweep = 0; sweep < 5; ++sweep) {
    JROT(0, 1, 2);
    JROT(0, 2, 1);
    JROT(1, 2, 0);
  }

  float d0 = K[0][0], d1 = K[1][1], d2 = K[2][2];
  float detV = V[0][0]*(V[1][1]*V[2][2] - V[1][2]*V[2][1])
             - V[0][1]*(V[1][0]*V[2][2] - V[1][2]*V[2][0])
             + V[0][2]*(V[1][0]*V[2][1] - V[1][1]*V[2][0]);
  float dsg = (detV < 0.0f) ? -1.0f : 1.0f;

  float R[3][3];
  if (d0 <= d1 && d0 <= d2) {
    FIN(1, 2, 0);
  } else if (d1 <= d0 && d1 <= d2) {
    FIN(2, 0, 1);
  } else {
    FIN(0, 1, 2);
  }

  float t0 = mx0 - (R[0][0]*my0 + R[0][1]*my1 + R[0][2]*my2);
  float t1 = mx1 - (R[1][0]*my0 + R[1][1]*my1 + R[1][2]*my2);
  float t2 = mx2 - (R[2][0]*my0 + R[2][1]*my1 + R[2][2]*my2);

  float* o = Rt + (size_t)p * 12;
  o[0] = R[0][0]; o[1] = R[0][1]; o[2] = R[0][2];
  o[3] = R[1][0]; o[4] = R[1][1]; o[5] = R[1][2];
  o[6] = R[2][0]; o[7] = R[2][1]; o[8] = R[2][2];
  o[9] = t0; o[10] = t1; o[11] = t2;
}

// ---------------- CSR build: histogram, 2-level scan, fill ----------------
__global__ __launch_bounds__(256) void k_hist(
    const int* __restrict__ groups, int* __restrict__ cnt) {
  int t = blockIdx.x * 256 + threadIdx.x;
  if (t < NE) atomicAdd(&cnt[groups[t]], 1);
}

__global__ __launch_bounds__(256) void k_scan1(
    const int* __restrict__ cnt, int* __restrict__ blockSums) {
  __shared__ int lds[4];
  int t = blockIdx.x * 256 + threadIdx.x;
  int v = (t < NN) ? cnt[t] : 0;
#pragma unroll
  for (int off = 32; off > 0; off >>= 1) v += __shfl_xor(v, off, 64);
  if ((threadIdx.x & 63) == 0) lds[threadIdx.x >> 6] = v;
  __syncthreads();
  if (threadIdx.x == 0)
    blockSums[blockIdx.x] = lds[0] + lds[1] + lds[2] + lds[3];
}

__global__ __launch_bounds__(512) void k_scan2(int* __restrict__ blockSums) {
  __shared__ int lds[512];
  int tid = threadIdx.x;
  int v = (tid < NBLK) ? blockSums[tid] : 0;
  lds[tid] = v;
  __syncthreads();
#pragma unroll
  for (int off = 1; off < 512; off <<= 1) {
    int add = (tid >= off) ? lds[tid - off] : 0;
    __syncthreads();
    lds[tid] += add;
    __syncthreads();
  }
  if (tid < NBLK) blockSums[tid] = lds[tid] - v;  // exclusive
}

__global__ __launch_bounds__(256) void k_scan3(
    const int* __restrict__ cnt, const int* __restrict__ blockSums,
    int* __restrict__ row_start, int* __restrict__ cursor) {
  __shared__ int lds[256];
  int tid = threadIdx.x;
  int t = blockIdx.x * 256 + tid;
  int v = (t < NN) ? cnt[t] : 0;
  lds[tid] = v;
  __syncthreads();
#pragma unroll
  for (int off = 1; off < 256; off <<= 1) {
    int add = (tid >= off) ? lds[tid - off] : 0;
    __syncthreads();
    lds[tid] += add;
    __syncthreads();
  }
  if (t < NN) {
    row_start[t] = lds[tid] - v + blockSums[blockIdx.x];
    cursor[t] = 0;  // zero the fill cursor here (aliased region)
  }
}

__global__ __launch_bounds__(256) void k_fill(
    const int* __restrict__ groups, const int* __restrict__ row_start,
    int* __restrict__ cursor, unsigned* __restrict__ entries) {
  int e = blockIdx.x * 256 + threadIdx.x;
  if (e >= NE) return;
  int n = groups[e];
  int pos = atomicAdd(&cursor[n], 1);
  entries[row_start[n] + pos] = (unsigned)(e >> 6);  // store g
}

// ---------------- Gather: out[b,n] = (1/c) * sum_g (R_{b,g} y_n + t_{b,g}) ----
__global__ __launch_bounds__(256) void k_gather(
    const float* __restrict__ tpl, const int* __restrict__ row_start,
    const int* __restrict__ cnt, const unsigned* __restrict__ entries,
    const float* __restrict__ Rt, float* __restrict__ out) {
  int n = blockIdx.x * 256 + threadIdx.x;
  if (n >= NN) return;
  int b = blockIdx.y;
  int s = row_start[n];
  int c = cnt[n];
  float y0 = tpl[n * 3 + 0], y1 = tpl[n * 3 + 1], y2 = tpl[n * 3 + 2];
  float p0 = 0.f, p1 = 0.f, p2 = 0.f;
  for (int j = 0; j < c; ++j) {
    unsigned g = entries[s + j];
    const float* rt = Rt + ((size_t)b * GN + g) * 12;
    p0 += rt[0] * y0 + rt[1] * y1 + rt[2] * y2 + rt[9];
    p1 += rt[3] * y0 + rt[4] * y1 + rt[5] * y2 + rt[10];
    p2 += rt[6] * y0 + rt[7] * y1 + rt[8] * y2 + rt[11];
  }
  float inv = 1.0f / fmaxf((float)c, 1.0f);
  float* o = out + ((size_t)b * NN + (size_t)n) * 3;
  o[0] = p0 * inv;
  o[1] = p1 * inv;
  o[2] = p2 * inv;
}

extern "C" void kernel_launch(void* const* d_in, const int* in_sizes, int n_in,
                              void* d_out, int out_size, void* d_ws, size_t ws_size,
                              hipStream_t stream) {
  const float* x      = (const float*)d_in[0];  // (B,N,3) f32
  const float* tpl    = (const float*)d_in[1];  // (N,3) f32
  const int*   groups = (const int*)d_in[2];    // (GN,GS) i32
  float* out = (float*)d_out;

  char* ws = (char*)d_ws;
  // Layout (total ~7.8 MB):
  //   [0, 3M)      Rt        NP*12 f32
  //   [3M, 7M)     Ht        NP*16 f32   (dead after k_svd; aliased below)
  //     alias [3M, 4M)      entries  NE u32   (written by k_fill, after k_svd)
  //     alias [4M, 4M+400K) cursor   NN i32   (zeroed in k_scan3, after k_svd)
  //   [7M, +400K)  cnt       NN i32
  //   [7M+400K, +400K) row_start NN i32
  //   [7M+800K, +2K)   blockSums
  float* Rt        = (float*)ws;
  float* Ht        = (float*)(ws + (size_t)3 * 1024 * 1024);
  unsigned* entries= (unsigned*)(ws + (size_t)3 * 1024 * 1024);
  int* cursor      = (int*)(ws + (size_t)4 * 1024 * 1024);
  int* cnt         = (int*)(ws + (size_t)7 * 1024 * 1024);
  int* row_start   = (int*)(ws + (size_t)7 * 1024 * 1024 + 400000);
  int* blockSums   = (int*)(ws + (size_t)7 * 1024 * 1024 + 800000);

  hipMemsetAsync(cnt, 0, (size_t)NN * sizeof(int), stream);

  // Order matters: k_stats/k_svd use Ht; k_scan3/k_fill reuse that region after.
  k_stats<<<NP / 4, 256, 0, stream>>>(x, tpl, groups, Ht);
  k_svd<<<NP / 256, 256, 0, stream>>>(Ht, Rt);
  k_hist<<<NE / 256, 256, 0, stream>>>(groups, cnt);
  k_scan1<<<NBLK, 256, 0, stream>>>(cnt, blockSums);
  k_scan2<<<1, 512, 0, stream>>>(blockSums);
  k_scan3<<<NBLK, 256, 0, stream>>>(cnt, blockSums, row_start, cursor);
  k_fill<<<NE / 256, 256, 0, stream>>>(groups, row_start, cursor, entries);
  k_gather<<<dim3(NBLK, BB), 256, 0, stream>>>(tpl, row_start, cnt, entries, Rt, out);
}

// Round 3
// 121.249 us; speedup vs baseline: 5.9772x; 1.2364x over previous
//
#include <hip/hip_runtime.h>
#include <math.h>

static constexpr int BB = 16;
static constexpr int NN = 100000;
static constexpr int GN = 4096;
static constexpr int GS = 64;
static constexpr int NP = BB * GN;       // 65536 problems
static constexpr int NE = GN * GS;       // 262144 entries
static constexpr int NBLK = (NN + 255) / 256;  // 391

__device__ __forceinline__ float wsum64(float v) {
#pragma unroll
  for (int off = 32; off > 0; off >>= 1) v += __shfl_xor(v, off, 64);
  return v;
}

// ---------- k_tpl: per-group template pack + muY + counts histogram ----------
// One wave per group: gather tpl once, write packed Yg (coalesced for k_stats),
// reduce muY, and fold in the counts histogram (each thread owns one entry).
__global__ __launch_bounds__(256) void k_tpl(
    const float* __restrict__ tpl, const int* __restrict__ groups,
    float* __restrict__ Yg, float* __restrict__ GmY, int* __restrict__ cnt) {
  int g    = blockIdx.x * 4 + (threadIdx.x >> 6);
  int lane = threadIdx.x & 63;
  int idx = groups[g * GS + lane];
  atomicAdd(&cnt[idx], 1);
  float y0 = tpl[idx * 3 + 0], y1 = tpl[idx * 3 + 1], y2 = tpl[idx * 3 + 2];
  float* o = Yg + ((size_t)g * GS + lane) * 3;
  o[0] = y0; o[1] = y1; o[2] = y2;
  float sy0 = wsum64(y0), sy1 = wsum64(y1), sy2 = wsum64(y2);
  if (lane == 0) {
    const float inv = 1.0f / 64.0f;
    float4 m = make_float4(sy0 * inv, sy1 * inv, sy2 * inv, 0.0f);
    *(float4*)(GmY + (size_t)g * 4) = m;
  }
}

// ---------- k_stats: 16-lane subgroups, 4 problems/wave, 4 points/lane ----------
__global__ __launch_bounds__(256) void k_stats(
    const float* __restrict__ x, const float* __restrict__ Yg,
    const float* __restrict__ GmY, const int* __restrict__ groups,
    float* __restrict__ Ht) {
  int wid4 = blockIdx.x * 4 + (threadIdx.x >> 6);  // wave id, 0..16383
  int lane = threadIdx.x & 63;
  int s    = lane >> 4;       // subgroup 0..3
  int l4   = lane & 15;       // lane within subgroup
  int p = wid4 * 4 + s;       // problem id
  int b = p >> 12;
  int g = p & (GN - 1);

  // 4 consecutive entries per lane
  int4 iv = *(const int4*)(groups + (size_t)g * GS + l4 * 4);
  const float4* yv = (const float4*)(Yg + ((size_t)g * GS + l4 * 4) * 3);
  float4 ya = yv[0], yb = yv[1], yc = yv[2];

  const float* xb = x + (size_t)b * NN * 3;
  float sx0 = 0.f, sx1 = 0.f, sx2 = 0.f;
  float h00 = 0.f, h01 = 0.f, h02 = 0.f;
  float h10 = 0.f, h11 = 0.f, h12 = 0.f;
  float h20 = 0.f, h21 = 0.f, h22 = 0.f;

#define ACC(Y0, Y1, Y2, IDX)                                   \
  {                                                            \
    const float* xp = xb + (size_t)(IDX) * 3;                  \
    float x0 = xp[0], x1 = xp[1], x2 = xp[2];                  \
    sx0 += x0; sx1 += x1; sx2 += x2;                           \
    h00 += (Y0) * x0; h01 += (Y0) * x1; h02 += (Y0) * x2;      \
    h10 += (Y1) * x0; h11 += (Y1) * x1; h12 += (Y1) * x2;      \
    h20 += (Y2) * x0; h21 += (Y2) * x1; h22 += (Y2) * x2;      \
  }
  ACC(ya.x, ya.y, ya.z, iv.x);
  ACC(ya.w, yb.x, yb.y, iv.y);
  ACC(yb.z, yb.w, yc.x, iv.z);
  ACC(yc.y, yc.z, yc.w, iv.w);
#undef ACC

  // butterfly within 16-lane subgroup (masks <16 never cross subgroups)
#define RED(V)                                                 \
  V += __shfl_xor(V, 8, 64); V += __shfl_xor(V, 4, 64);        \
  V += __shfl_xor(V, 2, 64); V += __shfl_xor(V, 1, 64);
  RED(sx0) RED(sx1) RED(sx2)
  RED(h00) RED(h01) RED(h02)
  RED(h10) RED(h11) RED(h12)
  RED(h20) RED(h21) RED(h22)
#undef RED

  if (l4 == 0) {
    const float inv = 1.0f / 64.0f;
    float4 m = *(const float4*)(GmY + (size_t)g * 4);  // muY
    float mx0 = sx0 * inv, mx1 = sx1 * inv, mx2 = sx2 * inv;
    // H[i][j] = sum(y_i x_j) - 64*muY_i*mx_j = h_ij - muY_i*sx_j
    float4 o0 = make_float4(mx0, mx1, mx2, h00 - m.x * sx0);
    float4 o1 = make_float4(h01 - m.x * sx1, h02 - m.x * sx2,
                            h10 - m.y * sx0, h11 - m.y * sx1);
    float4 o2 = make_float4(h12 - m.y * sx2, h20 - m.z * sx0,
                            h21 - m.z * sx1, h22 - m.z * sx2);
    float* o = Ht + (size_t)p * 12;
    *(float4*)(o + 0) = o0;
    *(float4*)(o + 4) = o1;
    *(float4*)(o + 8) = o2;
  }
}

// ---------------- k_svd: per-thread 3x3 SVD -> R, t ----------------
#define JROT(P, Q, RR)                                                        \
  {                                                                           \
    float apq = K[P][Q];                                                      \
    if (fabsf(apq) > 1e-30f) {                                                \
      float app = K[P][P], aqq = K[Q][Q];                                     \
      float tau = (aqq - app) / (2.0f * apq);                                 \
      float tt = copysignf(1.0f, tau) / (fabsf(tau) + sqrtf(1.0f + tau*tau)); \
      float cc = 1.0f / sqrtf(1.0f + tt * tt);                                \
      float ss = tt * cc;                                                     \
      K[P][P] = app - tt * apq;                                               \
      K[Q][Q] = aqq + tt * apq;                                               \
      K[P][Q] = 0.0f; K[Q][P] = 0.0f;                                         \
      float krp = K[RR][P], krq = K[RR][Q];                                   \
      K[RR][P] = cc * krp - ss * krq; K[P][RR] = K[RR][P];                    \
      K[RR][Q] = ss * krp + cc * krq; K[Q][RR] = K[RR][Q];                    \
      float v0p = V[0][P], v0q = V[0][Q];                                     \
      float v1p = V[1][P], v1q = V[1][Q];                                     \
      float v2p = V[2][P], v2q = V[2][Q];                                     \
      V[0][P] = cc * v0p - ss * v0q; V[0][Q] = ss * v0p + cc * v0q;           \
      V[1][P] = cc * v1p - ss * v1q; V[1][Q] = ss * v1p + cc * v1q;           \
      V[2][P] = cc * v2p - ss * v2q; V[2][Q] = ss * v2p + cc * v2q;           \
    }                                                                         \
  }

#define FIN(AA, BBi, CC)                                                      \
  {                                                                           \
    float va0 = V[0][AA], va1 = V[1][AA], va2 = V[2][AA];                     \
    float vb0 = V[0][BBi], vb1 = V[1][BBi], vb2 = V[2][BBi];                  \
    float vc0 = V[0][CC], vc1 = V[1][CC], vc2 = V[2][CC];                     \
    float ua0 = A[0][0]*va0 + A[0][1]*va1 + A[0][2]*va2;                      \
    float ua1 = A[1][0]*va0 + A[1][1]*va1 + A[1][2]*va2;                      \
    float ua2 = A[2][0]*va0 + A[2][1]*va1 + A[2][2]*va2;                      \
    float il = 1.0f / sqrtf(ua0*ua0 + ua1*ua1 + ua2*ua2 + 1e-30f);            \
    ua0 *= il; ua1 *= il; ua2 *= il;                                          \
    float ub0 = A[0][0]*vb0 + A[0][1]*vb1 + A[0][2]*vb2;                      \
    float ub1 = A[1][0]*vb0 + A[1][1]*vb1 + A[1][2]*vb2;                      \
    float ub2 = A[2][0]*vb0 + A[2][1]*vb1 + A[2][2]*vb2;                      \
    il = 1.0f / sqrtf(ub0*ub0 + ub1*ub1 + ub2*ub2 + 1e-30f);                  \
    ub0 *= il; ub1 *= il; ub2 *= il;                                          \
    float dd = ua0*ub0 + ua1*ub1 + ua2*ub2;                                   \
    ub0 -= dd * ua0; ub1 -= dd * ua1; ub2 -= dd * ua2;                        \
    il = 1.0f / sqrtf(ub0*ub0 + ub1*ub1 + ub2*ub2 + 1e-30f);                  \
    ub0 *= il; ub1 *= il; ub2 *= il;                                          \
    float uc0 = ua1*ub2 - ua2*ub1;                                            \
    float uc1 = ua2*ub0 - ua0*ub2;                                            \
    float uc2 = ua0*ub1 - ua1*ub0;                                            \
    R[0][0] = va0*ua0 + vb0*ub0 + dsg*vc0*uc0;                                \
    R[0][1] = va0*ua1 + vb0*ub1 + dsg*vc0*uc1;                                \
    R[0][2] = va0*ua2 + vb0*ub2 + dsg*vc0*uc2;                                \
    R[1][0] = va1*ua0 + vb1*ub0 + dsg*vc1*uc0;                                \
    R[1][1] = va1*ua1 + vb1*ub1 + dsg*vc1*uc1;                                \
    R[1][2] = va1*ua2 + vb1*ub2 + dsg*vc1*uc2;                                \
    R[2][0] = va2*ua0 + vb2*ub0 + dsg*vc2*uc0;                                \
    R[2][1] = va2*ua1 + vb2*ub1 + dsg*vc2*uc1;                                \
    R[2][2] = va2*ua2 + vb2*ub2 + dsg*vc2*uc2;                                \
  }

__global__ __launch_bounds__(256) void k_svd(
    const float* __restrict__ Ht, const float* __restrict__ GmY,
    float* __restrict__ Rt) {
  int p = blockIdx.x * 256 + threadIdx.x;
  if (p >= NP) return;
  int g = p & (GN - 1);
  const float* h = Ht + (size_t)p * 12;
  float4 f0 = *(const float4*)(h + 0);
  float4 f1 = *(const float4*)(h + 4);
  float4 f2 = *(const float4*)(h + 8);
  float4 m  = *(const float4*)(GmY + (size_t)g * 4);
  float mx0 = f0.x, mx1 = f0.y, mx2 = f0.z;
  float my0 = m.x, my1 = m.y, my2 = m.z;
  float A[3][3];
  A[0][0] = f0.w; A[0][1] = f1.x; A[0][2] = f1.y;
  A[1][0] = f1.z; A[1][1] = f1.w; A[1][2] = f2.x;
  A[2][0] = f2.y; A[2][1] = f2.z; A[2][2] = f2.w;

  float K[3][3];
#pragma unroll
  for (int i = 0; i < 3; ++i)
#pragma unroll
    for (int j = 0; j < 3; ++j)
      K[i][j] = A[0][i]*A[0][j] + A[1][i]*A[1][j] + A[2][i]*A[2][j];

  float V[3][3] = {{1.f,0.f,0.f},{0.f,1.f,0.f},{0.f,0.f,1.f}};
#pragma unroll
  for (int sweep = 0; sweep < 5; ++sweep) {
    JROT(0, 1, 2);
    JROT(0, 2, 1);
    JROT(1, 2, 0);
  }

  float d0 = K[0][0], d1 = K[1][1], d2 = K[2][2];
  float detV = V[0][0]*(V[1][1]*V[2][2] - V[1][2]*V[2][1])
             - V[0][1]*(V[1][0]*V[2][2] - V[1][2]*V[2][0])
             + V[0][2]*(V[1][0]*V[2][1] - V[1][1]*V[2][0]);
  float dsg = (detV < 0.0f) ? -1.0f : 1.0f;

  float R[3][3];
  if (d0 <= d1 && d0 <= d2) {
    FIN(1, 2, 0);
  } else if (d1 <= d0 && d1 <= d2) {
    FIN(2, 0, 1);
  } else {
    FIN(0, 1, 2);
  }

  float t0 = mx0 - (R[0][0]*my0 + R[0][1]*my1 + R[0][2]*my2);
  float t1 = mx1 - (R[1][0]*my0 + R[1][1]*my1 + R[1][2]*my2);
  float t2 = mx2 - (R[2][0]*my0 + R[2][1]*my1 + R[2][2]*my2);

  float* o = Rt + (size_t)p * 12;
  o[0] = R[0][0]; o[1] = R[0][1]; o[2] = R[0][2];
  o[3] = R[1][0]; o[4] = R[1][1]; o[5] = R[1][2];
  o[6] = R[2][0]; o[7] = R[2][1]; o[8] = R[2][2];
  o[9] = t0; o[10] = t1; o[11] = t2;
}

// ---------------- CSR build: 2-level scan + fill ----------------
__global__ __launch_bounds__(256) void k_scan1(
    const int* __restrict__ cnt, int* __restrict__ blockSums) {
  __shared__ int lds[4];
  int t = blockIdx.x * 256 + threadIdx.x;
  int v = (t < NN) ? cnt[t] : 0;
#pragma unroll
  for (int off = 32; off > 0; off >>= 1) v += __shfl_xor(v, off, 64);
  if ((threadIdx.x & 63) == 0) lds[threadIdx.x >> 6] = v;
  __syncthreads();
  if (threadIdx.x == 0)
    blockSums[blockIdx.x] = lds[0] + lds[1] + lds[2] + lds[3];
}

__global__ __launch_bounds__(512) void k_scan2(int* __restrict__ blockSums) {
  __shared__ int lds[512];
  int tid = threadIdx.x;
  int v = (tid < NBLK) ? blockSums[tid] : 0;
  lds[tid] = v;
  __syncthreads();
#pragma unroll
  for (int off = 1; off < 512; off <<= 1) {
    int add = (tid >= off) ? lds[tid - off] : 0;
    __syncthreads();
    lds[tid] += add;
    __syncthreads();
  }
  if (tid < NBLK) blockSums[tid] = lds[tid] - v;  // exclusive
}

__global__ __launch_bounds__(256) void k_scan3(
    const int* __restrict__ cnt, const int* __restrict__ blockSums,
    int* __restrict__ row_start, int* __restrict__ cursor) {
  __shared__ int lds[256];
  int tid = threadIdx.x;
  int t = blockIdx.x * 256 + tid;
  int v = (t < NN) ? cnt[t] : 0;
  lds[tid] = v;
  __syncthreads();
#pragma unroll
  for (int off = 1; off < 256; off <<= 1) {
    int add = (tid >= off) ? lds[tid - off] : 0;
    __syncthreads();
    lds[tid] += add;
    __syncthreads();
  }
  if (t < NN) {
    row_start[t] = lds[tid] - v + blockSums[blockIdx.x];
    cursor[t] = 0;
  }
}

__global__ __launch_bounds__(256) void k_fill(
    const int* __restrict__ groups, const int* __restrict__ row_start,
    int* __restrict__ cursor, unsigned* __restrict__ entries) {
  int e = blockIdx.x * 256 + threadIdx.x;
  if (e >= NE) return;
  int n = groups[e];
  int pos = atomicAdd(&cursor[n], 1);
  entries[row_start[n] + pos] = (unsigned)(e >> 6);  // store g
}

// ---------------- Gather ----------------
__global__ __launch_bounds__(256) void k_gather(
    const float* __restrict__ tpl, const int* __restrict__ row_start,
    const int* __restrict__ cnt, const unsigned* __restrict__ entries,
    const float* __restrict__ Rt, float* __restrict__ out) {
  int n = blockIdx.x * 256 + threadIdx.x;
  if (n >= NN) return;
  int b = blockIdx.y;
  int s = row_start[n];
  int c = cnt[n];
  float y0 = tpl[n * 3 + 0], y1 = tpl[n * 3 + 1], y2 = tpl[n * 3 + 2];
  float p0 = 0.f, p1 = 0.f, p2 = 0.f;
  for (int j = 0; j < c; ++j) {
    unsigned g = entries[s + j];
    const float* rt = Rt + ((size_t)b * GN + g) * 12;
    p0 += rt[0] * y0 + rt[1] * y1 + rt[2] * y2 + rt[9];
    p1 += rt[3] * y0 + rt[4] * y1 + rt[5] * y2 + rt[10];
    p2 += rt[6] * y0 + rt[7] * y1 + rt[8] * y2 + rt[11];
  }
  float inv = 1.0f / fmaxf((float)c, 1.0f);
  float* o = out + ((size_t)b * NN + (size_t)n) * 3;
  o[0] = p0 * inv;
  o[1] = p1 * inv;
  o[2] = p2 * inv;
}

extern "C" void kernel_launch(void* const* d_in, const int* in_sizes, int n_in,
                              void* d_out, int out_size, void* d_ws, size_t ws_size,
                              hipStream_t stream) {
  const float* x      = (const float*)d_in[0];  // (B,N,3) f32
  const float* tpl    = (const float*)d_in[1];  // (N,3) f32
  const int*   groups = (const int*)d_in[2];    // (GN,GS) i32
  float* out = (float*)d_out;

  char* ws = (char*)d_ws;
  // Layout (~6.9 MB), with lifetime-based aliasing:
  //   [0, 3M):   Yg (k_tpl -> k_stats), then Rt (k_svd -> k_gather).
  //              Safe: Yg is dead before k_svd writes Rt.
  //   [3M, 6M):  Ht (k_stats -> k_svd), then entries@3M (1MB, k_fill) and
  //              cursor@3M+1M (400KB, zeroed in k_scan3) — both after k_svd.
  //   [6M, +64K):   GmY (GN*4 f32)
  //   [6M+64K, ..): cnt, row_start (400KB each), blockSums (2KB)
  float* Yg        = (float*)ws;
  float* Rt        = (float*)ws;
  float* Ht        = (float*)(ws + (size_t)3 * 1024 * 1024);
  unsigned* entries= (unsigned*)(ws + (size_t)3 * 1024 * 1024);
  int* cursor      = (int*)(ws + (size_t)4 * 1024 * 1024);
  float* GmY       = (float*)(ws + (size_t)6 * 1024 * 1024);
  int* cnt         = (int*)(ws + (size_t)6 * 1024 * 1024 + 65536);
  int* row_start   = (int*)(ws + (size_t)6 * 1024 * 1024 + 65536 + 400000);
  int* blockSums   = (int*)(ws + (size_t)6 * 1024 * 1024 + 65536 + 800000);

  hipMemsetAsync(cnt, 0, (size_t)NN * sizeof(int), stream);

  k_tpl<<<GN / 4, 256, 0, stream>>>(tpl, groups, Yg, GmY, cnt);
  k_stats<<<NP / 16, 256, 0, stream>>>(x, Yg, GmY, groups, Ht);
  k_svd<<<NP / 256, 256, 0, stream>>>(Ht, GmY, Rt);
  k_scan1<<<NBLK, 256, 0, stream>>>(cnt, blockSums);
  k_scan2<<<1, 512, 0, stream>>>(blockSums);
  k_scan3<<<NBLK, 256, 0, stream>>>(cnt, blockSums, row_start, cursor);
  k_fill<<<NE / 256, 256, 0, stream>>>(groups, row_start, cursor, entries);
  k_gather<<<dim3(NBLK, BB), 256, 0, stream>>>(tpl, row_start, cnt, entries, Rt, out);
}

// Round 4
// 121.149 us; speedup vs baseline: 5.9822x; 1.0008x over previous
//
#include <hip/hip_runtime.h>
#include <math.h>

static constexpr int BB = 16;
static constexpr int NN = 100000;
static constexpr int GN = 4096;
static constexpr int GS = 64;
static constexpr int NP = BB * GN;       // 65536 problems
static constexpr int NE = GN * GS;       // 262144 entries
static constexpr int NBLK = (NN + 255) / 256;  // 391

__device__ __forceinline__ float wsum64(float v) {
#pragma unroll
  for (int off = 32; off > 0; off >>= 1) v += __shfl_xor(v, off, 64);
  return v;
}

// ---------- k_zero: zero the counts buffer (replaces 43us rocclr fill) ----------
__global__ __launch_bounds__(256) void k_zero(int4* __restrict__ cnt4) {
  int t = blockIdx.x * 256 + threadIdx.x;
  if (t < NN / 4) cnt4[t] = make_int4(0, 0, 0, 0);
}

// ---------- k_tpl: per-group template pack + muY + counts histogram ----------
__global__ __launch_bounds__(256) void k_tpl(
    const float* __restrict__ tpl, const int* __restrict__ groups,
    float* __restrict__ Yg, float* __restrict__ GmY, int* __restrict__ cnt) {
  int g    = blockIdx.x * 4 + (threadIdx.x >> 6);
  int lane = threadIdx.x & 63;
  int idx = groups[g * GS + lane];
  atomicAdd(&cnt[idx], 1);
  float y0 = tpl[idx * 3 + 0], y1 = tpl[idx * 3 + 1], y2 = tpl[idx * 3 + 2];
  float* o = Yg + ((size_t)g * GS + lane) * 3;
  o[0] = y0; o[1] = y1; o[2] = y2;
  float sy0 = wsum64(y0), sy1 = wsum64(y1), sy2 = wsum64(y2);
  if (lane == 0) {
    const float inv = 1.0f / 64.0f;
    float4 m = make_float4(sy0 * inv, sy1 * inv, sy2 * inv, 0.0f);
    *(float4*)(GmY + (size_t)g * 4) = m;
  }
}

// ---------- k_stats: 16-lane subgroups, 4 problems/wave, 4 points/lane ----------
__global__ __launch_bounds__(256) void k_stats(
    const float* __restrict__ x, const float* __restrict__ Yg,
    const float* __restrict__ GmY, const int* __restrict__ groups,
    float* __restrict__ Ht) {
  int wid4 = blockIdx.x * 4 + (threadIdx.x >> 6);  // wave id
  int lane = threadIdx.x & 63;
  int s    = lane >> 4;       // subgroup 0..3
  int l4   = lane & 15;       // lane within subgroup
  int p = wid4 * 4 + s;       // problem id
  int b = p >> 12;
  int g = p & (GN - 1);

  int4 iv = *(const int4*)(groups + (size_t)g * GS + l4 * 4);
  const float4* yv = (const float4*)(Yg + ((size_t)g * GS + l4 * 4) * 3);
  float4 ya = yv[0], yb = yv[1], yc = yv[2];

  const float* xb = x + (size_t)b * NN * 3;
  float sx0 = 0.f, sx1 = 0.f, sx2 = 0.f;
  float h00 = 0.f, h01 = 0.f, h02 = 0.f;
  float h10 = 0.f, h11 = 0.f, h12 = 0.f;
  float h20 = 0.f, h21 = 0.f, h22 = 0.f;

#define ACC(Y0, Y1, Y2, IDX)                                   \
  {                                                            \
    const float* xp = xb + (size_t)(IDX) * 3;                  \
    float x0 = xp[0], x1 = xp[1], x2 = xp[2];                  \
    sx0 += x0; sx1 += x1; sx2 += x2;                           \
    h00 += (Y0) * x0; h01 += (Y0) * x1; h02 += (Y0) * x2;      \
    h10 += (Y1) * x0; h11 += (Y1) * x1; h12 += (Y1) * x2;      \
    h20 += (Y2) * x0; h21 += (Y2) * x1; h22 += (Y2) * x2;      \
  }
  ACC(ya.x, ya.y, ya.z, iv.x);
  ACC(ya.w, yb.x, yb.y, iv.y);
  ACC(yb.z, yb.w, yc.x, iv.z);
  ACC(yc.y, yc.z, yc.w, iv.w);
#undef ACC

#define RED(V)                                                 \
  V += __shfl_xor(V, 8, 64); V += __shfl_xor(V, 4, 64);        \
  V += __shfl_xor(V, 2, 64); V += __shfl_xor(V, 1, 64);
  RED(sx0) RED(sx1) RED(sx2)
  RED(h00) RED(h01) RED(h02)
  RED(h10) RED(h11) RED(h12)
  RED(h20) RED(h21) RED(h22)
#undef RED

  if (l4 == 0) {
    const float inv = 1.0f / 64.0f;
    float4 m = *(const float4*)(GmY + (size_t)g * 4);  // muY
    float mx0 = sx0 * inv, mx1 = sx1 * inv, mx2 = sx2 * inv;
    float4 o0 = make_float4(mx0, mx1, mx2, h00 - m.x * sx0);
    float4 o1 = make_float4(h01 - m.x * sx1, h02 - m.x * sx2,
                            h10 - m.y * sx0, h11 - m.y * sx1);
    float4 o2 = make_float4(h12 - m.y * sx2, h20 - m.z * sx0,
                            h21 - m.z * sx1, h22 - m.z * sx2);
    float* o = Ht + (size_t)p * 12;
    *(float4*)(o + 0) = o0;
    *(float4*)(o + 4) = o1;
    *(float4*)(o + 8) = o2;
  }
}

// ---------------- k_svd: per-thread 3x3 SVD -> R, t ----------------
#define JROT(P, Q, RR)                                                        \
  {                                                                           \
    float apq = K[P][Q];                                                      \
    if (fabsf(apq) > 1e-30f) {                                                \
      float app = K[P][P], aqq = K[Q][Q];                                     \
      float tau = (aqq - app) / (2.0f * apq);                                 \
      float tt = copysignf(1.0f, tau) / (fabsf(tau) + sqrtf(1.0f + tau*tau)); \
      float cc = 1.0f / sqrtf(1.0f + tt * tt);                                \
      float ss = tt * cc;                                                     \
      K[P][P] = app - tt * apq;                                               \
      K[Q][Q] = aqq + tt * apq;                                               \
      K[P][Q] = 0.0f; K[Q][P] = 0.0f;                                         \
      float krp = K[RR][P], krq = K[RR][Q];                                   \
      K[RR][P] = cc * krp - ss * krq; K[P][RR] = K[RR][P];                    \
      K[RR][Q] = ss * krp + cc * krq; K[Q][RR] = K[RR][Q];                    \
      float v0p = V[0][P], v0q = V[0][Q];                                     \
      float v1p = V[1][P], v1q = V[1][Q];                                     \
      float v2p = V[2][P], v2q = V[2][Q];                                     \
      V[0][P] = cc * v0p - ss * v0q; V[0][Q] = ss * v0p + cc * v0q;           \
      V[1][P] = cc * v1p - ss * v1q; V[1][Q] = ss * v1p + cc * v1q;           \
      V[2][P] = cc * v2p - ss * v2q; V[2][Q] = ss * v2p + cc * v2q;           \
    }                                                                         \
  }

#define FIN(AA, BBi, CC)                                                      \
  {                                                                           \
    float va0 = V[0][AA], va1 = V[1][AA], va2 = V[2][AA];                     \
    float vb0 = V[0][BBi], vb1 = V[1][BBi], vb2 = V[2][BBi];                  \
    float vc0 = V[0][CC], vc1 = V[1][CC], vc2 = V[2][CC];                     \
    float ua0 = A[0][0]*va0 + A[0][1]*va1 + A[0][2]*va2;                      \
    float ua1 = A[1][0]*va0 + A[1][1]*va1 + A[1][2]*va2;                      \
    float ua2 = A[2][0]*va0 + A[2][1]*va1 + A[2][2]*va2;                      \
    float il = 1.0f / sqrtf(ua0*ua0 + ua1*ua1 + ua2*ua2 + 1e-30f);            \
    ua0 *= il; ua1 *= il; ua2 *= il;                                          \
    float ub0 = A[0][0]*vb0 + A[0][1]*vb1 + A[0][2]*vb2;                      \
    float ub1 = A[1][0]*vb0 + A[1][1]*vb1 + A[1][2]*vb2;                      \
    float ub2 = A[2][0]*vb0 + A[2][1]*vb1 + A[2][2]*vb2;                      \
    il = 1.0f / sqrtf(ub0*ub0 + ub1*ub1 + ub2*ub2 + 1e-30f);                  \
    ub0 *= il; ub1 *= il; ub2 *= il;                                          \
    float dd = ua0*ub0 + ua1*ub1 + ua2*ub2;                                   \
    ub0 -= dd * ua0; ub1 -= dd * ua1; ub2 -= dd * ua2;                        \
    il = 1.0f / sqrtf(ub0*ub0 + ub1*ub1 + ub2*ub2 + 1e-30f);                  \
    ub0 *= il; ub1 *= il; ub2 *= il;                                          \
    float uc0 = ua1*ub2 - ua2*ub1;                                            \
    float uc1 = ua2*ub0 - ua0*ub2;                                            \
    float uc2 = ua0*ub1 - ua1*ub0;                                            \
    R[0][0] = va0*ua0 + vb0*ub0 + dsg*vc0*uc0;                                \
    R[0][1] = va0*ua1 + vb0*ub1 + dsg*vc0*uc1;                                \
    R[0][2] = va0*ua2 + vb0*ub2 + dsg*vc0*uc2;                                \
    R[1][0] = va1*ua0 + vb1*ub0 + dsg*vc1*uc0;                                \
    R[1][1] = va1*ua1 + vb1*ub1 + dsg*vc1*uc1;                                \
    R[1][2] = va1*ua2 + vb1*ub2 + dsg*vc1*uc2;                                \
    R[2][0] = va2*ua0 + vb2*ub0 + dsg*vc2*uc0;                                \
    R[2][1] = va2*ua1 + vb2*ub1 + dsg*vc2*uc1;                                \
    R[2][2] = va2*ua2 + vb2*ub2 + dsg*vc2*uc2;                                \
  }

__global__ __launch_bounds__(256) void k_svd(
    const float* __restrict__ Ht, const float* __restrict__ GmY,
    float* __restrict__ Rt) {
  int p = blockIdx.x * 256 + threadIdx.x;
  if (p >= NP) return;
  int g = p & (GN - 1);
  const float* h = Ht + (size_t)p * 12;
  float4 f0 = *(const float4*)(h + 0);
  float4 f1 = *(const float4*)(h + 4);
  float4 f2 = *(const float4*)(h + 8);
  float4 m  = *(const float4*)(GmY + (size_t)g * 4);
  float mx0 = f0.x, mx1 = f0.y, mx2 = f0.z;
  float my0 = m.x, my1 = m.y, my2 = m.z;
  float A[3][3];
  A[0][0] = f0.w; A[0][1] = f1.x; A[0][2] = f1.y;
  A[1][0] = f1.z; A[1][1] = f1.w; A[1][2] = f2.x;
  A[2][0] = f2.y; A[2][1] = f2.z; A[2][2] = f2.w;

  float K[3][3];
#pragma unroll
  for (int i = 0; i < 3; ++i)
#pragma unroll
    for (int j = 0; j < 3; ++j)
      K[i][j] = A[0][i]*A[0][j] + A[1][i]*A[1][j] + A[2][i]*A[2][j];

  float V[3][3] = {{1.f,0.f,0.f},{0.f,1.f,0.f},{0.f,0.f,1.f}};
#pragma unroll
  for (int sweep = 0; sweep < 5; ++sweep) {
    JROT(0, 1, 2);
    JROT(0, 2, 1);
    JROT(1, 2, 0);
  }

  float d0 = K[0][0], d1 = K[1][1], d2 = K[2][2];
  float detV = V[0][0]*(V[1][1]*V[2][2] - V[1][2]*V[2][1])
             - V[0][1]*(V[1][0]*V[2][2] - V[1][2]*V[2][0])
             + V[0][2]*(V[1][0]*V[2][1] - V[1][1]*V[2][0]);
  float dsg = (detV < 0.0f) ? -1.0f : 1.0f;

  float R[3][3];
  if (d0 <= d1 && d0 <= d2) {
    FIN(1, 2, 0);
  } else if (d1 <= d0 && d1 <= d2) {
    FIN(2, 0, 1);
  } else {
    FIN(0, 1, 2);
  }

  float t0 = mx0 - (R[0][0]*my0 + R[0][1]*my1 + R[0][2]*my2);
  float t1 = mx1 - (R[1][0]*my0 + R[1][1]*my1 + R[1][2]*my2);
  float t2 = mx2 - (R[2][0]*my0 + R[2][1]*my1 + R[2][2]*my2);

  float* o = Rt + (size_t)p * 12;
  o[0] = R[0][0]; o[1] = R[0][1]; o[2] = R[0][2];
  o[3] = R[1][0]; o[4] = R[1][1]; o[5] = R[1][2];
  o[6] = R[2][0]; o[7] = R[2][1]; o[8] = R[2][2];
  o[9] = t0; o[10] = t1; o[11] = t2;
}

// ---------------- CSR build: 2-level scan + fill ----------------
__global__ __launch_bounds__(256) void k_scan1(
    const int* __restrict__ cnt, int* __restrict__ blockSums) {
  __shared__ int lds[4];
  int t = blockIdx.x * 256 + threadIdx.x;
  int v = (t < NN) ? cnt[t] : 0;
#pragma unroll
  for (int off = 32; off > 0; off >>= 1) v += __shfl_xor(v, off, 64);
  if ((threadIdx.x & 63) == 0) lds[threadIdx.x >> 6] = v;
  __syncthreads();
  if (threadIdx.x == 0)
    blockSums[blockIdx.x] = lds[0] + lds[1] + lds[2] + lds[3];
}

__global__ __launch_bounds__(512) void k_scan2(int* __restrict__ blockSums) {
  __shared__ int lds[512];
  int tid = threadIdx.x;
  int v = (tid < NBLK) ? blockSums[tid] : 0;
  lds[tid] = v;
  __syncthreads();
#pragma unroll
  for (int off = 1; off < 512; off <<= 1) {
    int add = (tid >= off) ? lds[tid - off] : 0;
    __syncthreads();
    lds[tid] += add;
    __syncthreads();
  }
  if (tid < NBLK) blockSums[tid] = lds[tid] - v;  // exclusive
}

__global__ __launch_bounds__(256) void k_scan3(
    const int* __restrict__ cnt, const int* __restrict__ blockSums,
    int* __restrict__ row_start, int* __restrict__ cursor) {
  __shared__ int lds[256];
  int tid = threadIdx.x;
  int t = blockIdx.x * 256 + tid;
  int v = (t < NN) ? cnt[t] : 0;
  lds[tid] = v;
  __syncthreads();
#pragma unroll
  for (int off = 1; off < 256; off <<= 1) {
    int add = (tid >= off) ? lds[tid - off] : 0;
    __syncthreads();
    lds[tid] += add;
    __syncthreads();
  }
  if (t < NN) {
    row_start[t] = lds[tid] - v + blockSums[blockIdx.x];
    cursor[t] = 0;
  }
}

__global__ __launch_bounds__(256) void k_fill(
    const int* __restrict__ groups, const int* __restrict__ row_start,
    int* __restrict__ cursor, unsigned* __restrict__ entries) {
  int e = blockIdx.x * 256 + threadIdx.x;
  if (e >= NE) return;
  int n = groups[e];
  int pos = atomicAdd(&cursor[n], 1);
  entries[row_start[n] + pos] = (unsigned)(e >> 6);  // store g
}

// ---------------- Gather ----------------
__global__ __launch_bounds__(256) void k_gather(
    const float* __restrict__ tpl, const int* __restrict__ row_start,
    const int* __restrict__ cnt, const unsigned* __restrict__ entries,
    const float* __restrict__ Rt, float* __restrict__ out) {
  int n = blockIdx.x * 256 + threadIdx.x;
  if (n >= NN) return;
  int b = blockIdx.y;
  int s = row_start[n];
  int c = cnt[n];
  float y0 = tpl[n * 3 + 0], y1 = tpl[n * 3 + 1], y2 = tpl[n * 3 + 2];
  float p0 = 0.f, p1 = 0.f, p2 = 0.f;
  for (int j = 0; j < c; ++j) {
    unsigned g = entries[s + j];
    const float* rt = Rt + ((size_t)b * GN + g) * 12;
    p0 += rt[0] * y0 + rt[1] * y1 + rt[2] * y2 + rt[9];
    p1 += rt[3] * y0 + rt[4] * y1 + rt[5] * y2 + rt[10];
    p2 += rt[6] * y0 + rt[7] * y1 + rt[8] * y2 + rt[11];
  }
  float inv = 1.0f / fmaxf((float)c, 1.0f);
  float* o = out + ((size_t)b * NN + (size_t)n) * 3;
  o[0] = p0 * inv;
  o[1] = p1 * inv;
  o[2] = p2 * inv;
}

extern "C" void kernel_launch(void* const* d_in, const int* in_sizes, int n_in,
                              void* d_out, int out_size, void* d_ws, size_t ws_size,
                              hipStream_t stream) {
  const float* x      = (const float*)d_in[0];  // (B,N,3) f32
  const float* tpl    = (const float*)d_in[1];  // (N,3) f32
  const int*   groups = (const int*)d_in[2];    // (GN,GS) i32
  float* out = (float*)d_out;

  char* ws = (char*)d_ws;
  // Layout (~6.9 MB), lifetime-based aliasing:
  //   [0, 3M):   Yg (k_tpl -> k_stats), then Rt (k_svd -> k_gather).
  //   [3M, 6M):  Ht (k_stats -> k_svd), then entries@3M (1MB) and
  //              cursor@4M (400KB, zeroed in k_scan3) — both after k_svd.
  //   [6M, +64K):   GmY
  //   [6M+64K, ..): cnt, row_start, blockSums
  float* Yg        = (float*)ws;
  float* Rt        = (float*)ws;
  float* Ht        = (float*)(ws + (size_t)3 * 1024 * 1024);
  unsigned* entries= (unsigned*)(ws + (size_t)3 * 1024 * 1024);
  int* cursor      = (int*)(ws + (size_t)4 * 1024 * 1024);
  float* GmY       = (float*)(ws + (size_t)6 * 1024 * 1024);
  int* cnt         = (int*)(ws + (size_t)6 * 1024 * 1024 + 65536);
  int* row_start   = (int*)(ws + (size_t)6 * 1024 * 1024 + 65536 + 400000);
  int* blockSums   = (int*)(ws + (size_t)6 * 1024 * 1024 + 65536 + 800000);

  k_zero<<<(NN / 4 + 255) / 256, 256, 0, stream>>>((int4*)cnt);
  k_tpl<<<GN / 4, 256, 0, stream>>>(tpl, groups, Yg, GmY, cnt);
  k_stats<<<NP / 16, 256, 0, stream>>>(x, Yg, GmY, groups, Ht);
  k_svd<<<NP / 256, 256, 0, stream>>>(Ht, GmY, Rt);
  k_scan1<<<NBLK, 256, 0, stream>>>(cnt, blockSums);
  k_scan2<<<1, 512, 0, stream>>>(blockSums);
  k_scan3<<<NBLK, 256, 0, stream>>>(cnt, blockSums, row_start, cursor);
  k_fill<<<NE / 256, 256, 0, stream>>>(groups, row_start, cursor, entries);
  k_gather<<<dim3(NBLK, BB), 256, 0, stream>>>(tpl, row_start, cnt, entries, Rt, out);
}

// Round 5
// 118.044 us; speedup vs baseline: 6.1395x; 1.0263x over previous
//
#include <hip/hip_runtime.h>
#include <math.h>

static constexpr int BB = 16;
static constexpr int NN = 100000;
static constexpr int GN = 4096;
static constexpr int GS = 64;
static constexpr int NP = BB * GN;       // 65536 problems
static constexpr int SLOT = 32;          // max occurrences per template point (actual max ~13)

__device__ __forceinline__ float wsum64(float v) {
#pragma unroll
  for (int off = 32; off > 0; off >>= 1) v += __shfl_xor(v, off, 64);
  return v;
}

// ---------- k_xpad: pad x (B,N,3) -> x4 (B,N,4) + zero cnt ----------
// 4 points per thread: 3 coalesced float4 reads -> 4 float4 writes.
__global__ __launch_bounds__(256) void k_xpad(
    const float4* __restrict__ x, float4* __restrict__ x4,
    int4* __restrict__ cnt4) {
  int t = blockIdx.x * 256 + threadIdx.x;
  if (t < NN / 4) cnt4[t] = make_int4(0, 0, 0, 0);
  if (t >= BB * NN / 4) return;
  float4 a = x[t * 3 + 0], b = x[t * 3 + 1], c = x[t * 3 + 2];
  x4[t * 4 + 0] = make_float4(a.x, a.y, a.z, 0.f);
  x4[t * 4 + 1] = make_float4(a.w, b.x, b.y, 0.f);
  x4[t * 4 + 2] = make_float4(b.z, b.w, c.x, 0.f);
  x4[t * 4 + 3] = make_float4(c.y, c.z, c.w, 0.f);
}

// ---------- k_tpl: template pack + muY + histogram + slot-table fill ----------
// One wave per group; lane = entry. cnt doubles as the slot cursor.
__global__ __launch_bounds__(256) void k_tpl(
    const float* __restrict__ tpl, const int* __restrict__ groups,
    float* __restrict__ Yg, float* __restrict__ GmY,
    int* __restrict__ cnt, int* __restrict__ ent) {
  int g    = blockIdx.x * 4 + (threadIdx.x >> 6);
  int lane = threadIdx.x & 63;
  int idx = groups[g * GS + lane];
  int pos = atomicAdd(&cnt[idx], 1);
  if (pos < SLOT) ent[idx * SLOT + pos] = g;
  float y0 = tpl[idx * 3 + 0], y1 = tpl[idx * 3 + 1], y2 = tpl[idx * 3 + 2];
  float* o = Yg + ((size_t)g * GS + lane) * 3;
  o[0] = y0; o[1] = y1; o[2] = y2;
  float sy0 = wsum64(y0), sy1 = wsum64(y1), sy2 = wsum64(y2);
  if (lane == 0) {
    const float inv = 1.0f / 64.0f;
    *(float4*)(GmY + (size_t)g * 4) =
        make_float4(sy0 * inv, sy1 * inv, sy2 * inv, 0.0f);
  }
}

// ---------- k_stats: 16-lane subgroups, 4 problems/wave, 4 points/lane ----------
__global__ __launch_bounds__(256) void k_stats(
    const float4* __restrict__ x4, const float* __restrict__ Yg,
    const float* __restrict__ GmY, const int* __restrict__ groups,
    float* __restrict__ Ht) {
  // XCD-bijective swizzle: 4096 blocks, 8 XCDs -> each XCD gets a contiguous
  // 512-block chunk (= 2 batch slices of x4, 3.2 MB, L2-resident).
  int bid  = (blockIdx.x & 7) * 512 + (blockIdx.x >> 3);
  int wid4 = bid * 4 + (threadIdx.x >> 6);  // wave id
  int lane = threadIdx.x & 63;
  int s    = lane >> 4;       // subgroup 0..3
  int l4   = lane & 15;       // lane within subgroup
  int p = wid4 * 4 + s;       // problem id
  int b = p >> 12;
  int g = p & (GN - 1);

  int4 iv = *(const int4*)(groups + (size_t)g * GS + l4 * 4);
  const float4* yv = (const float4*)(Yg + ((size_t)g * GS + l4 * 4) * 3);
  float4 ya = yv[0], yb = yv[1], yc = yv[2];

  const float4* xb4 = x4 + (size_t)b * NN;
  float sx0 = 0.f, sx1 = 0.f, sx2 = 0.f;
  float h00 = 0.f, h01 = 0.f, h02 = 0.f;
  float h10 = 0.f, h11 = 0.f, h12 = 0.f;
  float h20 = 0.f, h21 = 0.f, h22 = 0.f;

#define ACC(Y0, Y1, Y2, IDX)                                   \
  {                                                            \
    float4 xv = xb4[IDX];                                      \
    sx0 += xv.x; sx1 += xv.y; sx2 += xv.z;                     \
    h00 += (Y0) * xv.x; h01 += (Y0) * xv.y; h02 += (Y0) * xv.z;\
    h10 += (Y1) * xv.x; h11 += (Y1) * xv.y; h12 += (Y1) * xv.z;\
    h20 += (Y2) * xv.x; h21 += (Y2) * xv.y; h22 += (Y2) * xv.z;\
  }
  ACC(ya.x, ya.y, ya.z, iv.x);
  ACC(ya.w, yb.x, yb.y, iv.y);
  ACC(yb.z, yb.w, yc.x, iv.z);
  ACC(yc.y, yc.z, yc.w, iv.w);
#undef ACC

#define RED(V)                                                 \
  V += __shfl_xor(V, 8, 64); V += __shfl_xor(V, 4, 64);        \
  V += __shfl_xor(V, 2, 64); V += __shfl_xor(V, 1, 64);
  RED(sx0) RED(sx1) RED(sx2)
  RED(h00) RED(h01) RED(h02)
  RED(h10) RED(h11) RED(h12)
  RED(h20) RED(h21) RED(h22)
#undef RED

  if (l4 == 0) {
    const float inv = 1.0f / 64.0f;
    float4 m = *(const float4*)(GmY + (size_t)g * 4);  // muY
    float mx0 = sx0 * inv, mx1 = sx1 * inv, mx2 = sx2 * inv;
    float4 o0 = make_float4(mx0, mx1, mx2, h00 - m.x * sx0);
    float4 o1 = make_float4(h01 - m.x * sx1, h02 - m.x * sx2,
                            h10 - m.y * sx0, h11 - m.y * sx1);
    float4 o2 = make_float4(h12 - m.y * sx2, h20 - m.z * sx0,
                            h21 - m.z * sx1, h22 - m.z * sx2);
    float* o = Ht + (size_t)p * 12;
    *(float4*)(o + 0) = o0;
    *(float4*)(o + 4) = o1;
    *(float4*)(o + 8) = o2;
  }
}

// ---------------- k_svd: per-thread 3x3 SVD -> R, t ----------------
#define JROT(P, Q, RR)                                                        \
  {                                                                           \
    float apq = K[P][Q];                                                      \
    if (fabsf(apq) > 1e-30f) {                                                \
      float app = K[P][P], aqq = K[Q][Q];                                     \
      float tau = (aqq - app) / (2.0f * apq);                                 \
      float tt = copysignf(1.0f, tau) / (fabsf(tau) + sqrtf(1.0f + tau*tau)); \
      float cc = 1.0f / sqrtf(1.0f + tt * tt);                                \
      float ss = tt * cc;                                                     \
      K[P][P] = app - tt * apq;                                               \
      K[Q][Q] = aqq + tt * apq;                                               \
      K[P][Q] = 0.0f; K[Q][P] = 0.0f;                                         \
      float krp = K[RR][P], krq = K[RR][Q];                                   \
      K[RR][P] = cc * krp - ss * krq; K[P][RR] = K[RR][P];                    \
      K[RR][Q] = ss * krp + cc * krq; K[Q][RR] = K[RR][Q];                    \
      float v0p = V[0][P], v0q = V[0][Q];                                     \
      float v1p = V[1][P], v1q = V[1][Q];                                     \
      float v2p = V[2][P], v2q = V[2][Q];                                     \
      V[0][P] = cc * v0p - ss * v0q; V[0][Q] = ss * v0p + cc * v0q;           \
      V[1][P] = cc * v1p - ss * v1q; V[1][Q] = ss * v1p + cc * v1q;           \
      V[2][P] = cc * v2p - ss * v2q; V[2][Q] = ss * v2p + cc * v2q;           \
    }                                                                         \
  }

#define FIN(AA, BBi, CC)                                                      \
  {                                                                           \
    float va0 = V[0][AA], va1 = V[1][AA], va2 = V[2][AA];                     \
    float vb0 = V[0][BBi], vb1 = V[1][BBi], vb2 = V[2][BBi];                  \
    float vc0 = V[0][CC], vc1 = V[1][CC], vc2 = V[2][CC];                     \
    float ua0 = A[0][0]*va0 + A[0][1]*va1 + A[0][2]*va2;                      \
    float ua1 = A[1][0]*va0 + A[1][1]*va1 + A[1][2]*va2;                      \
    float ua2 = A[2][0]*va0 + A[2][1]*va1 + A[2][2]*va2;                      \
    float il = 1.0f / sqrtf(ua0*ua0 + ua1*ua1 + ua2*ua2 + 1e-30f);            \
    ua0 *= il; ua1 *= il; ua2 *= il;                                          \
    float ub0 = A[0][0]*vb0 + A[0][1]*vb1 + A[0][2]*vb2;                      \
    float ub1 = A[1][0]*vb0 + A[1][1]*vb1 + A[1][2]*vb2;                      \
    float ub2 = A[2][0]*vb0 + A[2][1]*vb1 + A[2][2]*vb2;                      \
    il = 1.0f / sqrtf(ub0*ub0 + ub1*ub1 + ub2*ub2 + 1e-30f);                  \
    ub0 *= il; ub1 *= il; ub2 *= il;                                          \
    float dd = ua0*ub0 + ua1*ub1 + ua2*ub2;                                   \
    ub0 -= dd * ua0; ub1 -= dd * ua1; ub2 -= dd * ua2;                        \
    il = 1.0f / sqrtf(ub0*ub0 + ub1*ub1 + ub2*ub2 + 1e-30f);                  \
    ub0 *= il; ub1 *= il; ub2 *= il;                                          \
    float uc0 = ua1*ub2 - ua2*ub1;                                            \
    float uc1 = ua2*ub0 - ua0*ub2;                                            \
    float uc2 = ua0*ub1 - ua1*ub0;                                            \
    R[0][0] = va0*ua0 + vb0*ub0 + dsg*vc0*uc0;                                \
    R[0][1] = va0*ua1 + vb0*ub1 + dsg*vc0*uc1;                                \
    R[0][2] = va0*ua2 + vb0*ub2 + dsg*vc0*uc2;                                \
    R[1][0] = va1*ua0 + vb1*ub0 + dsg*vc1*uc0;                                \
    R[1][1] = va1*ua1 + vb1*ub1 + dsg*vc1*uc1;                                \
    R[1][2] = va1*ua2 + vb1*ub2 + dsg*vc1*uc2;                                \
    R[2][0] = va2*ua0 + vb2*ub0 + dsg*vc2*uc0;                                \
    R[2][1] = va2*ua1 + vb2*ub1 + dsg*vc2*uc1;                                \
    R[2][2] = va2*ua2 + vb2*ub2 + dsg*vc2*uc2;                                \
  }

__global__ __launch_bounds__(256) void k_svd(
    const float* __restrict__ Ht, const float* __restrict__ GmY,
    float* __restrict__ Rt) {
  int p = blockIdx.x * 256 + threadIdx.x;
  if (p >= NP) return;
  int g = p & (GN - 1);
  const float* h = Ht + (size_t)p * 12;
  float4 f0 = *(const float4*)(h + 0);
  float4 f1 = *(const float4*)(h + 4);
  float4 f2 = *(const float4*)(h + 8);
  float4 m  = *(const float4*)(GmY + (size_t)g * 4);
  float mx0 = f0.x, mx1 = f0.y, mx2 = f0.z;
  float my0 = m.x, my1 = m.y, my2 = m.z;
  float A[3][3];
  A[0][0] = f0.w; A[0][1] = f1.x; A[0][2] = f1.y;
  A[1][0] = f1.z; A[1][1] = f1.w; A[1][2] = f2.x;
  A[2][0] = f2.y; A[2][1] = f2.z; A[2][2] = f2.w;

  float K[3][3];
#pragma unroll
  for (int i = 0; i < 3; ++i)
#pragma unroll
    for (int j = 0; j < 3; ++j)
      K[i][j] = A[0][i]*A[0][j] + A[1][i]*A[1][j] + A[2][i]*A[2][j];

  float V[3][3] = {{1.f,0.f,0.f},{0.f,1.f,0.f},{0.f,0.f,1.f}};
#pragma unroll
  for (int sweep = 0; sweep < 5; ++sweep) {
    JROT(0, 1, 2);
    JROT(0, 2, 1);
    JROT(1, 2, 0);
  }

  float d0 = K[0][0], d1 = K[1][1], d2 = K[2][2];
  float detV = V[0][0]*(V[1][1]*V[2][2] - V[1][2]*V[2][1])
             - V[0][1]*(V[1][0]*V[2][2] - V[1][2]*V[2][0])
             + V[0][2]*(V[1][0]*V[2][1] - V[1][1]*V[2][0]);
  float dsg = (detV < 0.0f) ? -1.0f : 1.0f;

  float R[3][3];
  if (d0 <= d1 && d0 <= d2) {
    FIN(1, 2, 0);
  } else if (d1 <= d0 && d1 <= d2) {
    FIN(2, 0, 1);
  } else {
    FIN(0, 1, 2);
  }

  float t0 = mx0 - (R[0][0]*my0 + R[0][1]*my1 + R[0][2]*my2);
  float t1 = mx1 - (R[1][0]*my0 + R[1][1]*my1 + R[1][2]*my2);
  float t2 = mx2 - (R[2][0]*my0 + R[2][1]*my1 + R[2][2]*my2);

  float* o = Rt + (size_t)p * 12;
  o[0] = R[0][0]; o[1] = R[0][1]; o[2] = R[0][2];
  o[3] = R[1][0]; o[4] = R[1][1]; o[5] = R[1][2];
  o[6] = R[2][0]; o[7] = R[2][1]; o[8] = R[2][2];
  o[9] = t0; o[10] = t1; o[11] = t2;
}

// ---------------- k_gather: 4 lanes per (b,n), entry-parallel ----------------
__global__ __launch_bounds__(256) void k_gather(
    const float* __restrict__ tpl, const int* __restrict__ cnt,
    const int* __restrict__ ent, const float* __restrict__ Rt,
    float* __restrict__ out) {
  int n  = blockIdx.x * 64 + (threadIdx.x >> 2);
  int j0 = threadIdx.x & 3;
  int b  = blockIdx.y;
  if (n >= NN) return;
  int cn = cnt[n];
  int c  = min(cn, SLOT);
  float y0 = tpl[n * 3 + 0], y1 = tpl[n * 3 + 1], y2 = tpl[n * 3 + 2];
  float p0 = 0.f, p1 = 0.f, p2 = 0.f;
  const float* Rb = Rt + (size_t)b * GN * 12;
  for (int j = j0; j < c; j += 4) {
    int g = ent[n * SLOT + j];
    const float* rt = Rb + (size_t)g * 12;
    float4 r0 = *(const float4*)(rt + 0);   // R00 R01 R02 R10
    float4 r1 = *(const float4*)(rt + 4);   // R11 R12 R20 R21
    float4 r2 = *(const float4*)(rt + 8);   // R22 t0  t1  t2
    p0 += r0.x * y0 + r0.y * y1 + r0.z * y2 + r2.y;
    p1 += r0.w * y0 + r1.x * y1 + r1.y * y2 + r2.z;
    p2 += r1.z * y0 + r1.w * y1 + r2.x * y2 + r2.w;
  }
  // reduce across the 4-lane group (xor 1,2 stay within the group)
  p0 += __shfl_xor(p0, 1, 64); p0 += __shfl_xor(p0, 2, 64);
  p1 += __shfl_xor(p1, 1, 64); p1 += __shfl_xor(p1, 2, 64);
  p2 += __shfl_xor(p2, 1, 64); p2 += __shfl_xor(p2, 2, 64);
  if (j0 == 0) {
    float inv = 1.0f / fmaxf((float)cn, 1.0f);
    float* o = out + ((size_t)b * NN + (size_t)n) * 3;
    o[0] = p0 * inv;
    o[1] = p1 * inv;
    o[2] = p2 * inv;
  }
}

extern "C" void kernel_launch(void* const* d_in, const int* in_sizes, int n_in,
                              void* d_out, int out_size, void* d_ws, size_t ws_size,
                              hipStream_t stream) {
  const float* x      = (const float*)d_in[0];  // (B,N,3) f32
  const float* tpl    = (const float*)d_in[1];  // (N,3) f32
  const int*   groups = (const int*)d_in[2];    // (GN,GS) i32
  float* out = (float*)d_out;

  char* ws = (char*)d_ws;
  // Layout (~45.2 MB total), lifetime aliasing:
  //   x4  [0, 25.6M)              k_xpad -> k_stats
  //   Yg  [25.6M, +3.15M)         k_tpl -> k_stats; then Rt (k_svd -> k_gather)
  //   Ht  [28.75M, +3.15M)        k_stats -> k_svd
  //   GmY [31.9M, +64K)
  //   cnt [.., +400K)             zeroed in k_xpad; cursor in k_tpl; read k_gather
  //   ent [.., +12.8M)            k_tpl -> k_gather
  size_t o_x4  = 0;
  size_t o_yg  = 25600000;
  size_t o_ht  = o_yg + 3145728;
  size_t o_gmy = o_ht + 3145728;
  size_t o_cnt = o_gmy + 65536;
  size_t o_ent = o_cnt + 400000;
  float* x4   = (float*)(ws + o_x4);
  float* Yg   = (float*)(ws + o_yg);
  float* Rt   = (float*)(ws + o_yg);
  float* Ht   = (float*)(ws + o_ht);
  float* GmY  = (float*)(ws + o_gmy);
  int*   cnt  = (int*)(ws + o_cnt);
  int*   ent  = (int*)(ws + o_ent);

  k_xpad<<<(BB * NN / 4 + 255) / 256, 256, 0, stream>>>(
      (const float4*)x, (float4*)x4, (int4*)cnt);
  k_tpl<<<GN / 4, 256, 0, stream>>>(tpl, groups, Yg, GmY, cnt, ent);
  k_stats<<<NP / 16, 256, 0, stream>>>((const float4*)x4, Yg, GmY, groups, Ht);
  k_svd<<<NP / 256, 256, 0, stream>>>(Ht, GmY, Rt);
  k_gather<<<dim3((NN + 63) / 64, BB), 256, 0, stream>>>(tpl, cnt, ent, Rt, out);
}